// Round 1
// 281.825 us; speedup vs baseline: 1.0115x; 1.0115x over previous
//
#include <hip/hip_runtime.h>
#include <type_traits>

// Problem constants (ExaoneFlashAttention): B=4, S=1024, T=4096, D_MODEL=2048,
// H=32, KVH=8, HD=64, GROUPS=4, SCALE=1/8. All bf16 MFMA, f32 accum.
// Attention scale * log2(e) folded into Wq transpose -> softmax in exp2 domain.
// Max-free softmax (logits bounded); RoPE fused into the QKV GEMM epilogue.

typedef __bf16 bf16x8 __attribute__((ext_vector_type(8)));
typedef __bf16 bf16x4 __attribute__((ext_vector_type(4)));
typedef float f32x4 __attribute__((ext_vector_type(4)));
typedef unsigned short u16;
typedef unsigned int u32;

#define DEVI __device__ __forceinline__

DEVI u16 f2bf(float f) {           // RNE f32->bf16 (finite inputs)
  u32 u = __builtin_bit_cast(u32, f);
  u += 0x7FFF + ((u >> 16) & 1);
  return (u16)(u >> 16);
}

// async global->LDS, 16B per lane. LDS dest must be wave-uniform base + lane*16.
DEVI void ld16_lds(const void* g, void* l) {
  __builtin_amdgcn_global_load_lds((const __attribute__((address_space(1))) u32*)g,
                                   (__attribute__((address_space(3))) u32*)l, 16, 0, 0);
}

// ---------------- elementwise f32 -> bf16 ----------------
__global__ __launch_bounds__(256) void convert_f32_bf16(const float* __restrict__ src,
                                                        u16* __restrict__ dst, int n4) {
  int i = blockIdx.x * 256 + threadIdx.x;
  if (i >= n4) return;
  float4 v = ((const float4*)src)[i];
  ushort4 o;
  o.x = f2bf(v.x); o.y = f2bf(v.y); o.z = f2bf(v.z); o.w = f2bf(v.w);
  ((ushort4*)dst)[i] = o;
}

// ---------------- transpose + convert + scale: src RxC f32 -> dst CxR bf16 ----------------
__global__ __launch_bounds__(256) void trans_f32_bf16(const float* __restrict__ src,
                                                      u16* __restrict__ dst, int R, int C,
                                                      float scale) {
  __shared__ float tile[32][33];
  int c0 = blockIdx.x * 32, r0 = blockIdx.y * 32;
  int tx = threadIdx.x & 31, ty = threadIdx.x >> 5;   // ty 0..7
#pragma unroll
  for (int i = 0; i < 32; i += 8)
    tile[ty + i][tx] = src[(size_t)(r0 + ty + i) * C + (c0 + tx)];
  __syncthreads();
#pragma unroll
  for (int i = 0; i < 32; i += 8)
    dst[(size_t)(c0 + ty + i) * R + (r0 + tx)] = f2bf(tile[tx][ty + i] * scale);
}

// ---------------- GEMM v2: C(MxN) = A(MxK) * BT(NxK)^T, bf16 in, f32 acc -------------
// 256xBN tile, 512 threads (8 waves, grid GM x GN), BK=64, double-buffered LDS.
// Deep-pipeline schedule: stage loads for K-tile t+1 are ISSUED at the top of
// iteration t (into the buffer freed by tile t-1) and only DRAINED at the
// closing __syncthreads() -> HBM/L2 latency hides under ~2500cy of MFMA.
// LDS rows are 128B = 8 chunks; both-sides swizzle chunk^(row&7): staged from a
// pre-swizzled global source (global_load_lds dest must be linear), read back
// with the same XOR -> conflict-free ds_read_b128 (measured 0 conflicts on the
// previous-kernel variant of this pattern).
// ROPE: rotary applied in-register before the bf16 pack (QKV gemm only; pair
// (d, d+32) lives in (acc[i][j], acc[i][j+2]) of the same lane since each
// wave's 64-col span is head-aligned). Only columns < 2560 (Q and K heads).
template <typename OutT, bool ROPE, int BN, int GM, int GN, int WM, int WN>
__global__ __launch_bounds__(512, 2) void gemm_bt(const u16* __restrict__ A,
                                                  const u16* __restrict__ BT,
                                                  OutT* __restrict__ C, int M, int N, int K,
                                                  const float* __restrict__ cs,
                                                  const float* __restrict__ sn) {
  static_assert(GM * GN == 8 && 16 * WM * GM == 256 && 16 * WN * GN == BN, "geom");
  __shared__ u16 As[2][256 * 64];
  __shared__ u16 Bs[2][BN * 64];
  const int tid = threadIdx.x;
  const int lane = tid & 63, wave = tid >> 6;
  const int quad = lane >> 4, l16 = lane & 15;
  const int m0 = blockIdx.y * 256, n0 = blockIdx.x * BN;
  const int wr = wave / GN, wc = wave % GN;

  f32x4 acc[WM][WN] = {};

  auto stageTile = [&](int t, int bufIdx) {
    const int k0 = t * 64;
    u16* Ad = &As[bufIdx][0];
    u16* Bd = &Bs[bufIdx][0];
#pragma unroll
    for (int i = 0; i < 4; ++i) {            // A: 256 rows * 8 chunks / 512 thr
      int id = i * 512 + tid;
      int row = id >> 3, ch = id & 7;
      int sch = ch ^ (row & 7);              // pre-swizzled global source chunk
      ld16_lds(A + (size_t)(m0 + row) * K + k0 + sch * 8, Ad + id * 8);
    }
#pragma unroll
    for (int i = 0; i < BN / 64; ++i) {      // B: BN rows * 8 chunks / 512 thr
      int id = i * 512 + tid;
      int row = id >> 3, ch = id & 7;
      int sch = ch ^ (row & 7);
      ld16_lds(BT + (size_t)(n0 + row) * K + k0 + sch * 8, Bd + id * 8);
    }
  };

  const int NT = K / 64;
  stageTile(0, 0);
  __syncthreads();                            // prologue: full drain once

  for (int t = 0; t < NT; ++t) {
    const int c = t & 1;
    if (t + 1 < NT) stageTile(t + 1, 1 - c);  // issue early (other buffer)...
    const u16* Ab = &As[c][0];
    const u16* Bb = &Bs[c][0];
#pragma unroll
    for (int ks = 0; ks < 2; ++ks) {
      bf16x8 bfv[WN];
#pragma unroll
      for (int j = 0; j < WN; ++j) {
        int rb = wc * (16 * WN) + j * 16 + l16;
        bfv[j] = *(const bf16x8*)&Bb[rb * 64 + (((ks * 4 + quad) ^ (rb & 7)) * 8)];
      }
#pragma unroll
      for (int mh = 0; mh < WM / 4; ++mh) {
        bf16x8 af[4];
#pragma unroll
        for (int i = 0; i < 4; ++i) {
          int r = wr * (16 * WM) + (mh * 4 + i) * 16 + l16;
          af[i] = *(const bf16x8*)&Ab[r * 64 + (((ks * 4 + quad) ^ (r & 7)) * 8)];
        }
        __builtin_amdgcn_s_setprio(1);
#pragma unroll
        for (int i = 0; i < 4; ++i)
#pragma unroll
          for (int j = 0; j < WN; ++j)
            acc[mh * 4 + i][j] =
                __builtin_amdgcn_mfma_f32_16x16x32_bf16(af[i], bfv[j], acc[mh * 4 + i][j], 0, 0, 0);
        __builtin_amdgcn_s_setprio(0);
      }
    }
    __syncthreads();   // ...drain late: vmcnt(0)+barrier after a full tile of MFMA
  }

  // ---- fused RoPE (QKV gemm, Q/K columns only; wave-uniform branch) ----
  if constexpr (ROPE) {
    if (n0 + wc * (16 * WN) < 2560) {
#pragma unroll
      for (int i = 0; i < WM; i++) {
        int t0 = m0 + wr * (16 * WM) + i * 16 + quad * 4;
#pragma unroll
        for (int jj = 0; jj < 2; jj++) {
          int d = jj * 16 + l16;            // head-dim 0..31
#pragma unroll
          for (int r = 0; r < 4; r++) {
            float cv = cs[(size_t)(t0 + r) * 32 + d];
            float sv = sn[(size_t)(t0 + r) * 32 + d];
            float x1 = acc[i][jj][r], x2 = acc[i][jj + 2][r];
            acc[i][jj][r] = x1 * cv - x2 * sv;
            acc[i][jj + 2][r] = x2 * cv + x1 * sv;
          }
        }
      }
    }
  }

  // epilogue: C/D layout col=lane&15, row=quad*4+r
#pragma unroll
  for (int i = 0; i < WM; i++) {
    int row = m0 + wr * (16 * WM) + i * 16 + quad * 4;
#pragma unroll
    for (int j = 0; j < WN; j++) {
      int col = n0 + wc * (16 * WN) + j * 16 + l16;
#pragma unroll
      for (int r = 0; r < 4; r++) {
        size_t off = (size_t)(row + r) * N + col;
        if constexpr (sizeof(OutT) == 2) C[off] = f2bf(acc[i][j][r]);
        else C[off] = acc[i][j][r];
      }
    }
  }
}

// ---------------- vkt_build: V -> transposed, chunk-swizzled, k-permuted tile images ----
__global__ __launch_bounds__(256) void vkt_build(const u16* __restrict__ qkv,
                                                 u16* __restrict__ vkt) {
  __shared__ u16 Vn[128 * 64];
  const int kt = blockIdx.x, kvh = blockIdx.y, b = blockIdx.z;
  const int tid = threadIdx.x;
  const u16* src = qkv + ((size_t)b * 1024 + kt * 128) * 3072 + 2560 + kvh * 64;
  {
    int tok = tid >> 1, hf = tid & 1;
    const uint4* s4 = (const uint4*)(src + (size_t)tok * 3072 + hf * 32);
    uint4* d4 = (uint4*)&Vn[tok * 64 + hf * 32];
#pragma unroll
    for (int j = 0; j < 4; j++) d4[j] = s4[j];
  }
  __syncthreads();
  u16* img = vkt + ((((size_t)b * 8 + kvh) * 8 + kt) << 13);   // 8192 u16 / image
#pragma unroll
  for (int i = 0; i < 4; i++) {
    int c = tid * 4 + i;                 // chunk index 0..1023
    int dd = c >> 4, chsw = c & 15;
    int ch = chsw ^ (dd & 15);
    u16 tmp[8];
#pragma unroll
    for (int p = 0; p < 8; p++) {
      int col = ch * 8 + p;
      int g = col >> 5, kl = col & 31;
      int kph = ((kl >> 2) & 1) * 16 + ((kl >> 4) & 1) * 8 + ((kl >> 3) & 1) * 4 + (kl & 3);
      tmp[p] = Vn[(g * 32 + kph) * 64 + dd];
    }
    *(uint4*)&img[c * 8] = *(const uint4*)tmp;
  }
}

// ---------------- flash attention v4 ----------------
// Grid (4, 32, 4) = 512 blocks = 2/CU. Two q-tiles per block (qtA=bx, qtB=7-bx):
// 9 tile-steps per block, K/V staged once for both. Transposed-score form,
// max-free exp2 softmax, P kept in registers via the k-permutation baked into
// the VkT images. K and VT double-buffered pure DMA. One barrier/iter.
// LDS: Ks 2x16KB + VT 2x16KB = 64KB -> 2 blocks/CU.
__global__ __launch_bounds__(256, 2) void flash_attn(const u16* __restrict__ qkv,
                                                     const u16* __restrict__ vkt,
                                                     u16* __restrict__ attn) {
  __shared__ u16 Ks[2][128 * 64];
  __shared__ u16 VT[2][64 * 128];

  const int tid = threadIdx.x;
  const int lane = tid & 63, wave = tid >> 6;
  const int quad = lane >> 4, l16 = lane & 15;
  const int qtA = blockIdx.x, qtB = 7 - blockIdx.x;
  const int h = blockIdx.y, b = blockIdx.z, kvh = h >> 2;
  const size_t tokBase = (size_t)b * 1024;
  const int qcol = h * 64, kcol = 2048 + kvh * 64;
  const int srow = tid >> 3, spc = tid & 7, ssc = spc ^ (srow & 7);

  auto stageK = [&](const u16* gbase, u16* L) {   // natural 128x64, swizzled chunks
#pragma unroll
    for (int i = 0; i < 4; i++)
      ld16_lds(gbase + (size_t)(srow + i * 32) * 3072 + ssc * 8, &L[tid * 8 + i * 2048]);
  };
  const u16* vimg = vkt + (((size_t)b * 8 + kvh) << 16);
  auto stageV = [&](int kt, u16* L) {             // pre-swizzled image: linear copy
    const u16* g = vimg + ((size_t)kt << 13);
#pragma unroll
    for (int i = 0; i < 4; i++)
      ld16_lds(g + i * 2048 + tid * 8, &L[tid * 8 + i * 2048]);
  };

  // ---- stage both Q tiles into the K buffers, extract fragments ----
  stageK(qkv + (tokBase + qtA * 128) * 3072 + qcol, Ks[0]);
  stageK(qkv + (tokBase + qtB * 128) * 3072 + qcol, Ks[1]);
  __syncthreads();
  bf16x8 qfA[2][2], qfB[2][2];   // B-frag: n=q=l16, kdim=d contiguous
#pragma unroll
  for (int nq = 0; nq < 2; nq++) {
    int qrow = wave * 32 + nq * 16 + l16;
#pragma unroll
    for (int ks = 0; ks < 2; ks++) {
      int c = (ks * 4 + quad) ^ (qrow & 7);
      qfA[nq][ks] = *(const bf16x8*)&Ks[0][qrow * 64 + c * 8];
      qfB[nq][ks] = *(const bf16x8*)&Ks[1][qrow * 64 + c * 8];
    }
  }
  __syncthreads();   // Q reads done before K DMA overwrites

  float lA[2] = {0.f, 0.f}, lB[2] = {0.f, 0.f};
  f32x4 oA[4][2] = {}, oB[4][2] = {};   // O^T: d=md*16+quad*4+r, q=nq*16+l16

  auto proc = [&](const bf16x8 (&kf)[2][2], const bf16x8 (&va)[4], const bf16x8 (&qf)[2][2],
                  f32x4 (&o)[4][2], float (&lacc)[2], bool msk, int c) {
    f32x4 s[2][2] = {};   // [nq][mkl]: k = (c*2+mkl)*16 + quad*4 + r, q = nq*16+l16
#pragma unroll
    for (int mkl = 0; mkl < 2; mkl++)
#pragma unroll
      for (int ks = 0; ks < 2; ks++) {
        s[0][mkl] = __builtin_amdgcn_mfma_f32_16x16x32_bf16(kf[mkl][ks], qf[0][ks], s[0][mkl], 0, 0, 0);
        s[1][mkl] = __builtin_amdgcn_mfma_f32_16x16x32_bf16(kf[mkl][ks], qf[1][ks], s[1][mkl], 0, 0, 0);
      }
    if (msk) {
#pragma unroll
      for (int nq = 0; nq < 2; nq++) {
        int q = wave * 32 + nq * 16 + l16;
#pragma unroll
        for (int mkl = 0; mkl < 2; mkl++)
#pragma unroll
          for (int r = 0; r < 4; r++)
            if ((c * 2 + mkl) * 16 + quad * 4 + r > q) s[nq][mkl][r] = -3e38f;
      }
    }
    bf16x8 pf[2];
#pragma unroll
    for (int nq = 0; nq < 2; nq++) {
      float a0 = 0.f;
#pragma unroll
      for (int mkl = 0; mkl < 2; mkl++)
#pragma unroll
        for (int r = 0; r < 4; r++) {
          float p = __builtin_amdgcn_exp2f(s[nq][mkl][r]);
          s[nq][mkl][r] = p;
          a0 += p;
        }
      lacc[nq] += a0;
      pf[nq][0] = (__bf16)s[nq][0][0]; pf[nq][1] = (__bf16)s[nq][0][1];
      pf[nq][2] = (__bf16)s[nq][0][2]; pf[nq][3] = (__bf16)s[nq][0][3];
      pf[nq][4] = (__bf16)s[nq][1][0]; pf[nq][5] = (__bf16)s[nq][1][1];
      pf[nq][6] = (__bf16)s[nq][1][2]; pf[nq][7] = (__bf16)s[nq][1][3];
    }
#pragma unroll
    for (int md = 0; md < 4; md++) {
      o[md][0] = __builtin_amdgcn_mfma_f32_16x16x32_bf16(va[md], pf[0], o[md][0], 0, 0, 0);
      o[md][1] = __builtin_amdgcn_mfma_f32_16x16x32_bf16(va[md], pf[1], o[md][1], 0, 0, 0);
    }
  };

  // ---- main loop: double-buffered K + VT DMA, one barrier per iteration ----
  stageK(qkv + tokBase * 3072 + kcol, Ks[0]);
  stageV(0, VT[0]);

  for (int kt = 0; kt <= qtB; kt++) {
    const int cur = kt & 1;
    __syncthreads();   // drains DMA for kt; all waves done with bufs[1-cur]
    if (kt < qtB) {
      stageK(qkv + (tokBase + (kt + 1) * 128) * 3072 + kcol, Ks[1 - cur]);
      stageV(kt + 1, VT[1 - cur]);
    }
    const bool doA = (kt <= qtA), mA = (kt == qtA), mB = (kt == qtB);
    const u16* K = Ks[cur];
    const u16* V = VT[cur];
#pragma unroll
    for (int c = 0; c < 4; c++) {
      bf16x8 kf[2][2];   // A-frag: m=krow=mk*16+l16, kdim=d
#pragma unroll
      for (int mkl = 0; mkl < 2; mkl++) {
        int krow = (c * 2 + mkl) * 16 + l16;
#pragma unroll
        for (int ks = 0; ks < 2; ks++)
          kf[mkl][ks] = *(const bf16x8*)&K[krow * 64 + ((ks * 4 + quad) ^ (krow & 7)) * 8];
      }
      bf16x8 va[4];      // A-frag V^T: m=d=md*16+l16, k-chunk c
#pragma unroll
      for (int md = 0; md < 4; md++) {
        int dd = md * 16 + l16;
        va[md] = *(const bf16x8*)&V[dd * 128 + ((c * 4 + quad) ^ l16) * 8];
      }
      proc(kf, va, qfB, oB, lB, mB, c);
      if (doA) proc(kf, va, qfA, oA, lA, mA, c);
    }
  }

  // ---- epilogue: reduce l across quads (2 shfls), O/l, b64 stores ----
  auto epilogue = [&](const f32x4 (&o)[4][2], const float (&lacc)[2], int qt_tile) {
#pragma unroll
    for (int nq = 0; nq < 2; nq++) {
      float l = lacc[nq];
      l += __shfl_xor(l, 16);
      l += __shfl_xor(l, 32);
      float inv = 1.0f / l;
      int t = qt_tile * 128 + wave * 32 + nq * 16 + l16;
      size_t rowOff = (tokBase + t) * 2048 + qcol;
#pragma unroll
      for (int md = 0; md < 4; md++) {
        bf16x4 w;
        w[0] = (__bf16)(o[md][nq][0] * inv);
        w[1] = (__bf16)(o[md][nq][1] * inv);
        w[2] = (__bf16)(o[md][nq][2] * inv);
        w[3] = (__bf16)(o[md][nq][3] * inv);
        *(bf16x4*)&attn[rowOff + md * 16 + quad * 4] = w;
      }
    }
  };
  epilogue(oB, lB, qtB);
  epilogue(oA, lA, qtA);
}

// ---------------- launch ----------------
extern "C" void kernel_launch(void* const* d_in, const int* in_sizes, int n_in,
                              void* d_out, int out_size, void* d_ws, size_t ws_size,
                              hipStream_t stream) {
  const float* hs = (const float*)d_in[0];
  const float* cs = (const float*)d_in[1];
  const float* sn = (const float*)d_in[2];
  const float* Wq = (const float*)d_in[3];
  const float* Wk = (const float*)d_in[4];
  const float* Wv = (const float*)d_in[5];
  const float* Wo = (const float*)d_in[6];
  float* out = (float*)d_out;

  char* ws = (char*)d_ws;
  u16* hsB   = (u16*)(ws);                  // 4096x2048 bf16 (dead after qkv GEMM)
  u16* vkt   = (u16*)(ws);                  // 4MB VkT images, built after qkv GEMM
  u16* wqkvT = (u16*)(ws + 16777216);       // 3072x2048 bf16 [WqT;WkT;WvT]
  u16* woT   = (u16*)(ws + 29360128);       // 2048x2048 bf16
  u16* qkv   = (u16*)(ws + 37748736);       // 4096x3072 bf16
  u16* attnB = (u16*)(ws + 62914560);       // 4096x2048 bf16

  // attention scale folded into Wq: 1/8 * log2(e)
  const float QSCALE = 0.18033688011112042f;

  convert_f32_bf16<<<8192, 256, 0, stream>>>(hs, hsB, 4096 * 2048 / 4);
  trans_f32_bf16<<<dim3(64, 64), 256, 0, stream>>>(Wq, wqkvT, 2048, 2048, QSCALE);
  trans_f32_bf16<<<dim3(16, 64), 256, 0, stream>>>(Wk, wqkvT + (size_t)2048 * 2048, 2048, 512, 1.0f);
  trans_f32_bf16<<<dim3(16, 64), 256, 0, stream>>>(Wv, wqkvT + (size_t)2560 * 2048, 2048, 512, 1.0f);
  trans_f32_bf16<<<dim3(64, 64), 256, 0, stream>>>(Wo, woT, 2048, 2048, 1.0f);

  // QKV: 256x256 tile, 8 waves (2x4), grid 12x16 = 192 blocks.
  gemm_bt<u16, true, 256, 2, 4, 8, 4><<<dim3(12, 16), 512, 0, stream>>>(
      hsB, wqkvT, qkv, 4096, 3072, 2048, cs, sn);
  vkt_build<<<dim3(8, 8, 4), 256, 0, stream>>>(qkv, vkt);
  flash_attn<<<dim3(4, 32, 4), 256, 0, stream>>>(qkv, vkt, attnB);
  // Wo: 256x128 tile, 8 waves (4x2), grid 16x16 = 256 blocks = 1/CU (full util).
  gemm_bt<float, false, 128, 4, 2, 4, 4><<<dim3(16, 16), 512, 0, stream>>>(
      attnB, woT, out, 4096, 2048, 2048, nullptr, nullptr);
}

// Round 2
// 276.840 us; speedup vs baseline: 1.0297x; 1.0180x over previous
//
#include <hip/hip_runtime.h>
#include <type_traits>

// Problem constants (ExaoneFlashAttention): B=4, S=1024, T=4096, D_MODEL=2048,
// H=32, KVH=8, HD=64, GROUPS=4, SCALE=1/8. All bf16 MFMA, f32 accum.
// Attention scale * log2(e) folded into Wq transpose -> softmax in exp2 domain.
// Max-free softmax (logits bounded); RoPE fused into the QKV GEMM epilogue.

typedef __bf16 bf16x8 __attribute__((ext_vector_type(8)));
typedef __bf16 bf16x4 __attribute__((ext_vector_type(4)));
typedef float f32x4 __attribute__((ext_vector_type(4)));
typedef unsigned short u16;
typedef unsigned int u32;

#define DEVI __device__ __forceinline__

DEVI u16 f2bf(float f) {           // RNE f32->bf16 (finite inputs)
  u32 u = __builtin_bit_cast(u32, f);
  u += 0x7FFF + ((u >> 16) & 1);
  return (u16)(u >> 16);
}

// async global->LDS, 16B per lane. LDS dest must be wave-uniform base + lane*16.
DEVI void ld16_lds(const void* g, void* l) {
  __builtin_amdgcn_global_load_lds((const __attribute__((address_space(1))) u32*)g,
                                   (__attribute__((address_space(3))) u32*)l, 16, 0, 0);
}

template <int N> DEVI void waitvm() {   // counted vmcnt (T4) — compile-time immediate
  if constexpr (N == 0) asm volatile("s_waitcnt vmcnt(0)" ::: "memory");
  else if constexpr (N == 3) asm volatile("s_waitcnt vmcnt(3)" ::: "memory");
  else if constexpr (N == 4) asm volatile("s_waitcnt vmcnt(4)" ::: "memory");
  else static_assert(N == 0, "unsupported vmcnt");
}
DEVI void lgkm0() {                     // rule #18: sched_barrier after the wait
  asm volatile("s_waitcnt lgkmcnt(0)" ::: "memory");
  __builtin_amdgcn_sched_barrier(0);
}
DEVI void barrier() { __builtin_amdgcn_s_barrier(); }

// ---------------- elementwise f32 -> bf16 ----------------
__global__ __launch_bounds__(256) void convert_f32_bf16(const float* __restrict__ src,
                                                        u16* __restrict__ dst, int n4) {
  int i = blockIdx.x * 256 + threadIdx.x;
  if (i >= n4) return;
  float4 v = ((const float4*)src)[i];
  ushort4 o;
  o.x = f2bf(v.x); o.y = f2bf(v.y); o.z = f2bf(v.z); o.w = f2bf(v.w);
  ((ushort4*)dst)[i] = o;
}

// ---------------- transpose + convert + scale: src RxC f32 -> dst CxR bf16 ----------------
__global__ __launch_bounds__(256) void trans_f32_bf16(const float* __restrict__ src,
                                                      u16* __restrict__ dst, int R, int C,
                                                      float scale) {
  __shared__ float tile[32][33];
  int c0 = blockIdx.x * 32, r0 = blockIdx.y * 32;
  int tx = threadIdx.x & 31, ty = threadIdx.x >> 5;   // ty 0..7
#pragma unroll
  for (int i = 0; i < 32; i += 8)
    tile[ty + i][tx] = src[(size_t)(r0 + ty + i) * C + (c0 + tx)];
  __syncthreads();
#pragma unroll
  for (int i = 0; i < 32; i += 8)
    dst[(size_t)(c0 + ty + i) * R + (r0 + tx)] = f2bf(tile[tx][ty + i] * scale);
}

// ---------------- GEMM v3: m201 8-phase counted-vmcnt schedule --------------------------
// C(Mx N) = A(MxK) * BT(NxK)^T, bf16 in, f32 acc. BM=256 x BN (256 or 128), BK=64,
// 512 thr = 8 waves (2M x 4N), per-wave output 128 x (BN/4). Double-buffered LDS,
// halves of 128 A-rows / BN/2 B-rows. Per iteration (2 K-tiles = 8 phases), each
// phase: {ds_read reg subtile | issue 1 half-tile global_load_lds -> barrier ->
// lgkmcnt(0) -> setprio(1) -> MFMA quadrant -> setprio(0) -> barrier}. vmcnt is
// counted (VMP = loads of 2 half-tiles legitimately in flight) and only waited at
// phases 4/8 — loads stay in flight across barriers (T3+T4). Stage stagger (all
// verified against last-reader phases): P1:Ah1(T+1) P2:Bh1(T+1) (just-in-time,
// land by P4 vmcnt) | P3:Bh0(T+2) P4:Ah0(T+2) (B read thru P2, A thru P3) |
// P5:Bh1(T+2) P6:Ah1(T+2) | P7:Bh0(T+3) P8:Ah0(T+3).
// Chunk swizzle (T2): LDS[row][ch] holds global chunk ch^(row&7), staged via
// pre-swizzled global source (global_load_lds dest must be linear), read back with
// the same XOR -> conflict-free ds_read_b128 (0 conflicts measured).
// ROPE: rotary in-register pre-pack (QKV only); pair (d,d+32) = (acc[i][j],
// acc[i][j+2]) of same lane since each wave's 64-col span is head-aligned.
template <typename OutT, bool ROPE, int BN>
__global__ __launch_bounds__(512, 2) void gemm8(const u16* __restrict__ A,
                                                const u16* __restrict__ BT,
                                                OutT* __restrict__ C, int M, int N, int K,
                                                const float* __restrict__ cs,
                                                const float* __restrict__ sn) {
  constexpr int WN = BN / 64;    // n-frags per wave: 4 (BN=256) or 2 (BN=128)
  constexpr int NH = WN / 2;     // n-frags per n-subhalf
  constexpr int LB = BN / 128;   // loads/thread per B half-tile (A is always 2)
  constexpr int VMP = 2 + LB;    // steady-state vmcnt: one A-half + one B-half in flight
  __shared__ u16 As[2][256 * 64];
  __shared__ u16 Bs[2][BN * 64];
  const int tid = threadIdx.x;
  const int lane = tid & 63, wave = tid >> 6;
  const int quad = lane >> 4, l16 = lane & 15;
  const int m0 = blockIdx.y * 256, n0 = blockIdx.x * BN;
  const int wr = wave >> 2, wc = wave & 3;   // 2M x 4N wave grid

  f32x4 acc[8][WN] = {};

  // ---- staging: one half-tile per call, 16B/lane linear dest, swizzled source ----
  auto stageA = [&](int t, int h) {          // A K-tile t, half h(128 rows) -> buf t&1
    u16* D = &As[t & 1][h * 8192];
    const u16* G = A + (size_t)m0 * K + t * 64;
#pragma unroll
    for (int i = 0; i < 2; ++i) {
      int id = i * 512 + tid;
      int row = h * 128 + (id >> 3), ch = id & 7;
      ld16_lds(G + (size_t)row * K + (ch ^ (row & 7)) * 8, D + id * 8);
    }
  };
  auto stageB = [&](int t, int h) {          // B K-tile t, half h(BN/2 rows) -> buf t&1
    u16* D = &Bs[t & 1][h * (BN / 2) * 64];
    const u16* G = BT + (size_t)n0 * K + t * 64;
#pragma unroll
    for (int i = 0; i < LB; ++i) {
      int id = i * 512 + tid;
      int row = h * (BN / 2) + (id >> 3), ch = id & 7;
      ld16_lds(G + (size_t)row * K + (ch ^ (row & 7)) * 8, D + id * 8);
    }
  };

  // ---- register fragment loads (swizzled ds_read_b128) ----
  bf16x8 af[4][2], bv0[NH][2], bv1[NH][2];
  auto ldA = [&](int msub, int d) {
#pragma unroll
    for (int i = 0; i < 4; ++i)
#pragma unroll
      for (int ks = 0; ks < 2; ++ks) {
        int r = wr * 128 + msub * 64 + i * 16 + l16;
        af[i][ks] = *(const bf16x8*)&As[d][r * 64 + (((ks * 4 + quad) ^ (r & 7)) * 8)];
      }
  };
  auto ldB = [&](bf16x8 (&bv)[NH][2], int nsub, int d) {
#pragma unroll
    for (int j = 0; j < NH; ++j)
#pragma unroll
      for (int ks = 0; ks < 2; ++ks) {
        int rb = wc * (16 * WN) + (nsub * NH + j) * 16 + l16;
        bv[j][ks] = *(const bf16x8*)&Bs[d][rb * 64 + (((ks * 4 + quad) ^ (rb & 7)) * 8)];
      }
  };
  auto mm = [&](const bf16x8 (&bv)[NH][2], int mo, int no) {   // one quadrant (T5 wrap)
    __builtin_amdgcn_s_setprio(1);
#pragma unroll
    for (int i = 0; i < 4; ++i)
#pragma unroll
      for (int j = 0; j < NH; ++j)
#pragma unroll
        for (int ks = 0; ks < 2; ++ks)
          acc[mo + i][no + j] =
              __builtin_amdgcn_mfma_f32_16x16x32_bf16(af[i][ks], bv[j][ks], acc[mo + i][no + j], 0, 0, 0);
    __builtin_amdgcn_s_setprio(0);
  };

  const int NT = K / 64;   // 32 (even) for both GEMMs

  // ---- prologue: tile0 fully + {Bh0,Ah0} of tile1; oldest-first vmcnt leaves 2 halves flying
  stageA(0, 0); stageA(0, 1); stageB(0, 0); stageB(0, 1);
  stageB(1, 0); stageA(1, 0);
  waitvm<VMP>();
  barrier();

#pragma unroll 1
  for (int T = 0; T < NT; T += 2) {
    const bool pf = (T + 2 < NT);
    // ================ phases 1-4 : tile T in buf0 ================
    ldA(0, 0); ldB(bv0, 0, 0);           // P1
    stageA(T + 1, 1);                    //   JIT: Ah1(T+1) -> buf1
    barrier(); lgkm0();
    mm(bv0, 0, 0);
    barrier();

    ldB(bv1, 1, 0);                      // P2
    stageB(T + 1, 1);                    //   JIT: Bh1(T+1) -> buf1
    barrier(); lgkm0();
    mm(bv1, 0, NH);
    barrier();

    ldA(1, 0);                           // P3
    if (pf) stageB(T + 2, 0);            //   Bh0(T+2) -> buf0 (B reads done @P2)
    barrier(); lgkm0();
    mm(bv1, 4, NH);
    barrier();

    if (pf) { stageA(T + 2, 0); waitvm<VMP>(); }   // P4: Ah0(T+2) (A reads done @P3)
    else waitvm<0>();
    barrier();                           //   tile T+1 now fully landed
    __builtin_amdgcn_sched_barrier(0);
    mm(bv0, 4, 0);
    barrier();

    // ================ phases 5-8 : tile T+1 in buf1 ================
    ldA(0, 1); ldB(bv0, 0, 1);           // P5
    if (pf) stageB(T + 2, 1);            //   Bh1(T+2) -> buf0 (all buf0 reads done)
    barrier(); lgkm0();
    mm(bv0, 0, 0);
    barrier();

    ldB(bv1, 1, 1);                      // P6
    if (pf) stageA(T + 2, 1);            //   Ah1(T+2) -> buf0
    barrier(); lgkm0();
    mm(bv1, 0, NH);
    barrier();

    ldA(1, 1);                           // P7
    if (pf) stageB(T + 3, 0);            //   Bh0(T+3) -> buf1 (B reads done @P6)
    barrier(); lgkm0();
    mm(bv1, 4, NH);
    barrier();

    if (pf) {                            // P8: Ah0(T+3) -> buf1 (A reads done @P7)
      stageA(T + 3, 0);
      waitvm<VMP>();                     //   tile T+2 fully landed for next iter
      barrier();
      __builtin_amdgcn_sched_barrier(0);
      mm(bv0, 4, 0);
      barrier();
    } else {
      mm(bv0, 4, 0);                     // last iteration: no more LDS traffic
    }
  }

  // ---- fused RoPE (QKV gemm, Q/K columns only; wave-uniform branch) ----
  if constexpr (ROPE) {
    if (n0 + wc * (16 * WN) < 2560) {
#pragma unroll
      for (int i = 0; i < 8; i++) {
        int t0 = m0 + wr * 128 + i * 16 + quad * 4;
#pragma unroll
        for (int jj = 0; jj < 2; jj++) {
          int d = jj * 16 + l16;            // head-dim 0..31
#pragma unroll
          for (int r = 0; r < 4; r++) {
            float cv = cs[(size_t)(t0 + r) * 32 + d];
            float sv = sn[(size_t)(t0 + r) * 32 + d];
            float x1 = acc[i][jj][r], x2 = acc[i][jj + 2][r];
            acc[i][jj][r] = x1 * cv - x2 * sv;
            acc[i][jj + 2][r] = x2 * cv + x1 * sv;
          }
        }
      }
    }
  }

  // epilogue: C/D layout col=lane&15, row=quad*4+r
#pragma unroll
  for (int i = 0; i < 8; i++) {
    int row = m0 + wr * 128 + i * 16 + quad * 4;
#pragma unroll
    for (int j = 0; j < WN; j++) {
      int col = n0 + wc * (16 * WN) + j * 16 + l16;
#pragma unroll
      for (int r = 0; r < 4; r++) {
        size_t off = (size_t)(row + r) * N + col;
        if constexpr (sizeof(OutT) == 2) C[off] = f2bf(acc[i][j][r]);
        else C[off] = acc[i][j][r];
      }
    }
  }
}

// ---------------- vkt_build: V -> transposed, chunk-swizzled, k-permuted tile images ----
__global__ __launch_bounds__(256) void vkt_build(const u16* __restrict__ qkv,
                                                 u16* __restrict__ vkt) {
  __shared__ u16 Vn[128 * 64];
  const int kt = blockIdx.x, kvh = blockIdx.y, b = blockIdx.z;
  const int tid = threadIdx.x;
  const u16* src = qkv + ((size_t)b * 1024 + kt * 128) * 3072 + 2560 + kvh * 64;
  {
    int tok = tid >> 1, hf = tid & 1;
    const uint4* s4 = (const uint4*)(src + (size_t)tok * 3072 + hf * 32);
    uint4* d4 = (uint4*)&Vn[tok * 64 + hf * 32];
#pragma unroll
    for (int j = 0; j < 4; j++) d4[j] = s4[j];
  }
  __syncthreads();
  u16* img = vkt + ((((size_t)b * 8 + kvh) * 8 + kt) << 13);   // 8192 u16 / image
#pragma unroll
  for (int i = 0; i < 4; i++) {
    int c = tid * 4 + i;                 // chunk index 0..1023
    int dd = c >> 4, chsw = c & 15;
    int ch = chsw ^ (dd & 15);
    u16 tmp[8];
#pragma unroll
    for (int p = 0; p < 8; p++) {
      int col = ch * 8 + p;
      int g = col >> 5, kl = col & 31;
      int kph = ((kl >> 2) & 1) * 16 + ((kl >> 4) & 1) * 8 + ((kl >> 3) & 1) * 4 + (kl & 3);
      tmp[p] = Vn[(g * 32 + kph) * 64 + dd];
    }
    *(uint4*)&img[c * 8] = *(const uint4*)tmp;
  }
}

// ---------------- flash attention v4 ----------------
// Grid (4, 32, 4) = 512 blocks = 2/CU. Two q-tiles per block (qtA=bx, qtB=7-bx):
// 9 tile-steps per block, K/V staged once for both. Transposed-score form,
// max-free exp2 softmax, P kept in registers via the k-permutation baked into
// the VkT images. K and VT double-buffered pure DMA. One barrier/iter.
// LDS: Ks 2x16KB + VT 2x16KB = 64KB -> 2 blocks/CU.
__global__ __launch_bounds__(256, 2) void flash_attn(const u16* __restrict__ qkv,
                                                     const u16* __restrict__ vkt,
                                                     u16* __restrict__ attn) {
  __shared__ u16 Ks[2][128 * 64];
  __shared__ u16 VT[2][64 * 128];

  const int tid = threadIdx.x;
  const int lane = tid & 63, wave = tid >> 6;
  const int quad = lane >> 4, l16 = lane & 15;
  const int qtA = blockIdx.x, qtB = 7 - blockIdx.x;
  const int h = blockIdx.y, b = blockIdx.z, kvh = h >> 2;
  const size_t tokBase = (size_t)b * 1024;
  const int qcol = h * 64, kcol = 2048 + kvh * 64;
  const int srow = tid >> 3, spc = tid & 7, ssc = spc ^ (srow & 7);

  auto stageK = [&](const u16* gbase, u16* L) {   // natural 128x64, swizzled chunks
#pragma unroll
    for (int i = 0; i < 4; i++)
      ld16_lds(gbase + (size_t)(srow + i * 32) * 3072 + ssc * 8, &L[tid * 8 + i * 2048]);
  };
  const u16* vimg = vkt + (((size_t)b * 8 + kvh) << 16);
  auto stageV = [&](int kt, u16* L) {             // pre-swizzled image: linear copy
    const u16* g = vimg + ((size_t)kt << 13);
#pragma unroll
    for (int i = 0; i < 4; i++)
      ld16_lds(g + i * 2048 + tid * 8, &L[tid * 8 + i * 2048]);
  };

  // ---- stage both Q tiles into the K buffers, extract fragments ----
  stageK(qkv + (tokBase + qtA * 128) * 3072 + qcol, Ks[0]);
  stageK(qkv + (tokBase + qtB * 128) * 3072 + qcol, Ks[1]);
  __syncthreads();
  bf16x8 qfA[2][2], qfB[2][2];   // B-frag: n=q=l16, kdim=d contiguous
#pragma unroll
  for (int nq = 0; nq < 2; nq++) {
    int qrow = wave * 32 + nq * 16 + l16;
#pragma unroll
    for (int ks = 0; ks < 2; ks++) {
      int c = (ks * 4 + quad) ^ (qrow & 7);
      qfA[nq][ks] = *(const bf16x8*)&Ks[0][qrow * 64 + c * 8];
      qfB[nq][ks] = *(const bf16x8*)&Ks[1][qrow * 64 + c * 8];
    }
  }
  __syncthreads();   // Q reads done before K DMA overwrites

  float lA[2] = {0.f, 0.f}, lB[2] = {0.f, 0.f};
  f32x4 oA[4][2] = {}, oB[4][2] = {};   // O^T: d=md*16+quad*4+r, q=nq*16+l16

  auto proc = [&](const bf16x8 (&kf)[2][2], const bf16x8 (&va)[4], const bf16x8 (&qf)[2][2],
                  f32x4 (&o)[4][2], float (&lacc)[2], bool msk, int c) {
    f32x4 s[2][2] = {};   // [nq][mkl]: k = (c*2+mkl)*16 + quad*4 + r, q = nq*16+l16
#pragma unroll
    for (int mkl = 0; mkl < 2; mkl++)
#pragma unroll
      for (int ks = 0; ks < 2; ks++) {
        s[0][mkl] = __builtin_amdgcn_mfma_f32_16x16x32_bf16(kf[mkl][ks], qf[0][ks], s[0][mkl], 0, 0, 0);
        s[1][mkl] = __builtin_amdgcn_mfma_f32_16x16x32_bf16(kf[mkl][ks], qf[1][ks], s[1][mkl], 0, 0, 0);
      }
    if (msk) {
#pragma unroll
      for (int nq = 0; nq < 2; nq++) {
        int q = wave * 32 + nq * 16 + l16;
#pragma unroll
        for (int mkl = 0; mkl < 2; mkl++)
#pragma unroll
          for (int r = 0; r < 4; r++)
            if ((c * 2 + mkl) * 16 + quad * 4 + r > q) s[nq][mkl][r] = -3e38f;
      }
    }
    bf16x8 pf[2];
#pragma unroll
    for (int nq = 0; nq < 2; nq++) {
      float a0 = 0.f;
#pragma unroll
      for (int mkl = 0; mkl < 2; mkl++)
#pragma unroll
        for (int r = 0; r < 4; r++) {
          float p = __builtin_amdgcn_exp2f(s[nq][mkl][r]);
          s[nq][mkl][r] = p;
          a0 += p;
        }
      lacc[nq] += a0;
      pf[nq][0] = (__bf16)s[nq][0][0]; pf[nq][1] = (__bf16)s[nq][0][1];
      pf[nq][2] = (__bf16)s[nq][0][2]; pf[nq][3] = (__bf16)s[nq][0][3];
      pf[nq][4] = (__bf16)s[nq][1][0]; pf[nq][5] = (__bf16)s[nq][1][1];
      pf[nq][6] = (__bf16)s[nq][1][2]; pf[nq][7] = (__bf16)s[nq][1][3];
    }
#pragma unroll
    for (int md = 0; md < 4; md++) {
      o[md][0] = __builtin_amdgcn_mfma_f32_16x16x32_bf16(va[md], pf[0], o[md][0], 0, 0, 0);
      o[md][1] = __builtin_amdgcn_mfma_f32_16x16x32_bf16(va[md], pf[1], o[md][1], 0, 0, 0);
    }
  };

  // ---- main loop: double-buffered K + VT DMA, one barrier per iteration ----
  stageK(qkv + tokBase * 3072 + kcol, Ks[0]);
  stageV(0, VT[0]);

  for (int kt = 0; kt <= qtB; kt++) {
    const int cur = kt & 1;
    __syncthreads();   // drains DMA for kt; all waves done with bufs[1-cur]
    if (kt < qtB) {
      stageK(qkv + (tokBase + (kt + 1) * 128) * 3072 + kcol, Ks[1 - cur]);
      stageV(kt + 1, VT[1 - cur]);
    }
    const bool doA = (kt <= qtA), mA = (kt == qtA), mB = (kt == qtB);
    const u16* K = Ks[cur];
    const u16* V = VT[cur];
#pragma unroll
    for (int c = 0; c < 4; c++) {
      bf16x8 kf[2][2];   // A-frag: m=krow=mk*16+l16, kdim=d
#pragma unroll
      for (int mkl = 0; mkl < 2; mkl++) {
        int krow = (c * 2 + mkl) * 16 + l16;
#pragma unroll
        for (int ks = 0; ks < 2; ks++)
          kf[mkl][ks] = *(const bf16x8*)&K[krow * 64 + ((ks * 4 + quad) ^ (krow & 7)) * 8];
      }
      bf16x8 va[4];      // A-frag V^T: m=d=md*16+l16, k-chunk c
#pragma unroll
      for (int md = 0; md < 4; md++) {
        int dd = md * 16 + l16;
        va[md] = *(const bf16x8*)&V[dd * 128 + ((c * 4 + quad) ^ l16) * 8];
      }
      proc(kf, va, qfB, oB, lB, mB, c);
      if (doA) proc(kf, va, qfA, oA, lA, mA, c);
    }
  }

  // ---- epilogue: reduce l across quads (2 shfls), O/l, b64 stores ----
  auto epilogue = [&](const f32x4 (&o)[4][2], const float (&lacc)[2], int qt_tile) {
#pragma unroll
    for (int nq = 0; nq < 2; nq++) {
      float l = lacc[nq];
      l += __shfl_xor(l, 16);
      l += __shfl_xor(l, 32);
      float inv = 1.0f / l;
      int t = qt_tile * 128 + wave * 32 + nq * 16 + l16;
      size_t rowOff = (tokBase + t) * 2048 + qcol;
#pragma unroll
      for (int md = 0; md < 4; md++) {
        bf16x4 w;
        w[0] = (__bf16)(o[md][nq][0] * inv);
        w[1] = (__bf16)(o[md][nq][1] * inv);
        w[2] = (__bf16)(o[md][nq][2] * inv);
        w[3] = (__bf16)(o[md][nq][3] * inv);
        *(bf16x4*)&attn[rowOff + md * 16 + quad * 4] = w;
      }
    }
  };
  epilogue(oB, lB, qtB);
  epilogue(oA, lA, qtA);
}

// ---------------- launch ----------------
extern "C" void kernel_launch(void* const* d_in, const int* in_sizes, int n_in,
                              void* d_out, int out_size, void* d_ws, size_t ws_size,
                              hipStream_t stream) {
  const float* hs = (const float*)d_in[0];
  const float* cs = (const float*)d_in[1];
  const float* sn = (const float*)d_in[2];
  const float* Wq = (const float*)d_in[3];
  const float* Wk = (const float*)d_in[4];
  const float* Wv = (const float*)d_in[5];
  const float* Wo = (const float*)d_in[6];
  float* out = (float*)d_out;

  char* ws = (char*)d_ws;
  u16* hsB   = (u16*)(ws);                  // 4096x2048 bf16 (dead after qkv GEMM)
  u16* vkt   = (u16*)(ws);                  // 4MB VkT images, built after qkv GEMM
  u16* wqkvT = (u16*)(ws + 16777216);       // 3072x2048 bf16 [WqT;WkT;WvT]
  u16* woT   = (u16*)(ws + 29360128);       // 2048x2048 bf16
  u16* qkv   = (u16*)(ws + 37748736);       // 4096x3072 bf16
  u16* attnB = (u16*)(ws + 62914560);       // 4096x2048 bf16

  // attention scale folded into Wq: 1/8 * log2(e)
  const float QSCALE = 0.18033688011112042f;

  convert_f32_bf16<<<8192, 256, 0, stream>>>(hs, hsB, 4096 * 2048 / 4);
  trans_f32_bf16<<<dim3(64, 64), 256, 0, stream>>>(Wq, wqkvT, 2048, 2048, QSCALE);
  trans_f32_bf16<<<dim3(16, 64), 256, 0, stream>>>(Wk, wqkvT + (size_t)2048 * 2048, 2048, 512, 1.0f);
  trans_f32_bf16<<<dim3(16, 64), 256, 0, stream>>>(Wv, wqkvT + (size_t)2560 * 2048, 2048, 512, 1.0f);
  trans_f32_bf16<<<dim3(64, 64), 256, 0, stream>>>(Wo, woT, 2048, 2048, 1.0f);

  // QKV: 256x256 tile, 8-phase schedule, grid 12x16 = 192 blocks.
  gemm8<u16, true, 256><<<dim3(12, 16), 512, 0, stream>>>(
      hsB, wqkvT, qkv, 4096, 3072, 2048, cs, sn);
  vkt_build<<<dim3(8, 8, 4), 256, 0, stream>>>(qkv, vkt);
  flash_attn<<<dim3(4, 32, 4), 256, 0, stream>>>(qkv, vkt, attnB);
  // Wo: 256x128 tile, 8-phase, grid 16x16 = 256 blocks = 1/CU (full util).
  gemm8<float, false, 128><<<dim3(16, 16), 512, 0, stream>>>(
      attnB, woT, out, 4096, 2048, 2048, nullptr, nullptr);
}

// Round 4
// 268.282 us; speedup vs baseline: 1.0626x; 1.0319x over previous
//
#include <hip/hip_runtime.h>
#include <type_traits>

// Problem constants (ExaoneFlashAttention): B=4, S=1024, T=4096, D_MODEL=2048,
// H=32, KVH=8, HD=64, GROUPS=4, SCALE=1/8. All bf16 MFMA, f32 accum.
// Attention scale * log2(e) folded into Wq transpose -> softmax in exp2 domain.
// Max-free softmax (logits bounded); RoPE fused into the QKV GEMM epilogue.

typedef __bf16 bf16x8 __attribute__((ext_vector_type(8)));
typedef __bf16 bf16x4 __attribute__((ext_vector_type(4)));
typedef float f32x4 __attribute__((ext_vector_type(4)));
typedef unsigned short u16;
typedef unsigned int u32;

#define DEVI __device__ __forceinline__

DEVI u16 f2bf(float f) {           // RNE f32->bf16 (finite inputs)
  u32 u = __builtin_bit_cast(u32, f);
  u += 0x7FFF + ((u >> 16) & 1);
  return (u16)(u >> 16);
}

// async global->LDS, 16B per lane. LDS dest must be wave-uniform base + lane*16.
DEVI void ld16_lds(const void* g, void* l) {
  __builtin_amdgcn_global_load_lds((const __attribute__((address_space(1))) u32*)g,
                                   (__attribute__((address_space(3))) u32*)l, 16, 0, 0);
}

template <int N> DEVI void waitvm() {   // counted vmcnt (T4) — compile-time immediate
  if constexpr (N == 0) asm volatile("s_waitcnt vmcnt(0)" ::: "memory");
  else if constexpr (N == 6) asm volatile("s_waitcnt vmcnt(6)" ::: "memory");
  else if constexpr (N == 8) asm volatile("s_waitcnt vmcnt(8)" ::: "memory");
  else static_assert(N == 0, "unsupported vmcnt");
}
DEVI void lgkm0() {                     // rule #18: sched_barrier after the wait
  asm volatile("s_waitcnt lgkmcnt(0)" ::: "memory");
  __builtin_amdgcn_sched_barrier(0);
}
DEVI void barrier() { __builtin_amdgcn_s_barrier(); }

// ---------------- elementwise f32 -> bf16 ----------------
__global__ __launch_bounds__(256) void convert_f32_bf16(const float* __restrict__ src,
                                                        u16* __restrict__ dst, int n4) {
  int i = blockIdx.x * 256 + threadIdx.x;
  if (i >= n4) return;
  float4 v = ((const float4*)src)[i];
  ushort4 o;
  o.x = f2bf(v.x); o.y = f2bf(v.y); o.z = f2bf(v.z); o.w = f2bf(v.w);
  ((ushort4*)dst)[i] = o;
}

// ---------------- transpose + convert + scale: src RxC f32 -> dst CxR bf16 ----------------
__global__ __launch_bounds__(256) void trans_f32_bf16(const float* __restrict__ src,
                                                      u16* __restrict__ dst, int R, int C,
                                                      float scale) {
  __shared__ float tile[32][33];
  int c0 = blockIdx.x * 32, r0 = blockIdx.y * 32;
  int tx = threadIdx.x & 31, ty = threadIdx.x >> 5;   // ty 0..7
#pragma unroll
  for (int i = 0; i < 32; i += 8)
    tile[ty + i][tx] = src[(size_t)(r0 + ty + i) * C + (c0 + tx)];
  __syncthreads();
#pragma unroll
  for (int i = 0; i < 32; i += 8)
    dst[(size_t)(c0 + ty + i) * R + (r0 + tx)] = f2bf(tile[tx][ty + i] * scale);
}

// ---------------- GEMM v4: 8-phase, DEEP counted-vmcnt pipeline ------------------------
// C(MxN) = A(MxK) * BT(NxK)^T, bf16 in, f32 acc. BM=256 x BN (256 or 128), BK=64,
// 512 thr = 8 waves (2M x 4N), per-wave output 128 x (BN/4). Double-buffered LDS.
// Buffer lifetimes within phases 1-4 (tile T in buf0): both B halves of buf0 dead
// after P2, both A halves dead after P3. So tile T+2 is issued ENTIRELY at
// P3 (2 B halves) + P4 (2 A halves), tile T+3 entirely at P7/P8; nothing issued
// at P1/P2. The counted wait at P4 (for tile T+1, needed by P5) then covers loads
// issued in the PREVIOUS iteration's P7/P8 -> 4-5 phases (~1000 cy) of latency
// cover vs ~900 cy HBM miss (round-2's JIT P1/P2 stagger gave only ~2 phases ->
// measured stall, 88.9us). Wait value VMW = one full tile in flight = 4+2*LB.
// vmcnt NEVER drains to 0 in the steady-state loop (T4).
// Chunk swizzle (T2): LDS[row][ch] holds global chunk ch^(row&7), staged via
// pre-swizzled global source (global_load_lds dest must be linear), read back with
// the same XOR -> conflict-free ds_read_b128 (0 conflicts measured).
// XCD swizzle (T1): grid %8==0 (192/256 blocks), contiguous tile chunks per XCD.
// ROPE: rotary in-register pre-pack (QKV only); pair (d,d+32) = (acc[i][j],
// acc[i][j+2]) of same lane since each wave's 64-col span is head-aligned.
template <typename OutT, bool ROPE, int BN>
__global__ __launch_bounds__(512, 2) void gemm8(const u16* __restrict__ A,
                                                const u16* __restrict__ BT,
                                                OutT* __restrict__ C, int M, int N, int K,
                                                const float* __restrict__ cs,
                                                const float* __restrict__ sn) {
  constexpr int WN = BN / 64;    // n-frags per wave: 4 (BN=256) or 2 (BN=128)
  constexpr int NH = WN / 2;     // n-frags per n-subhalf
  constexpr int LB = BN / 128;   // loads/thread per B half-tile stage call
  constexpr int VMW = 4 + 2 * LB;  // one full K-tile in flight (A:4 + B:2*LB loads)
  __shared__ u16 As[2][256 * 64];
  __shared__ u16 Bs[2][BN * 64];
  const int tid = threadIdx.x;
  const int lane = tid & 63, wave = tid >> 6;
  const int quad = lane >> 4, l16 = lane & 15;

  // ---- XCD-aware block swizzle (bijective: nwg % 8 == 0 for both grids) ----
  const int nwg = gridDim.x * gridDim.y;
  const int bid = blockIdx.y * gridDim.x + blockIdx.x;
  const int swz = (bid & 7) * (nwg >> 3) + (bid >> 3);
  const int m0 = (swz / gridDim.x) * 256, n0 = (swz % gridDim.x) * BN;
  const int wr = wave >> 2, wc = wave & 3;   // 2M x 4N wave grid

  f32x4 acc[8][WN] = {};

  // ---- staging: one half-tile per call, 16B/lane linear dest, swizzled source ----
  auto stageA = [&](int t, int h) {          // A K-tile t, half h(128 rows) -> buf t&1
    u16* D = &As[t & 1][h * 8192];
    const u16* G = A + (size_t)m0 * K + t * 64;
#pragma unroll
    for (int i = 0; i < 2; ++i) {
      int id = i * 512 + tid;
      int row = h * 128 + (id >> 3), ch = id & 7;
      ld16_lds(G + (size_t)row * K + (ch ^ (row & 7)) * 8, D + id * 8);
    }
  };
  auto stageB = [&](int t, int h) {          // B K-tile t, half h(BN/2 rows) -> buf t&1
    u16* D = &Bs[t & 1][h * (BN / 2) * 64];
    const u16* G = BT + (size_t)n0 * K + t * 64;
#pragma unroll
    for (int i = 0; i < LB; ++i) {
      int id = i * 512 + tid;
      int row = h * (BN / 2) + (id >> 3), ch = id & 7;
      ld16_lds(G + (size_t)row * K + (ch ^ (row & 7)) * 8, D + id * 8);
    }
  };

  // ---- register fragment loads (swizzled ds_read_b128) ----
  bf16x8 af[4][2], bv0[NH][2], bv1[NH][2];
  auto ldA = [&](int msub, int d) {
#pragma unroll
    for (int i = 0; i < 4; ++i)
#pragma unroll
      for (int ks = 0; ks < 2; ++ks) {
        int r = wr * 128 + msub * 64 + i * 16 + l16;
        af[i][ks] = *(const bf16x8*)&As[d][r * 64 + (((ks * 4 + quad) ^ (r & 7)) * 8)];
      }
  };
  auto ldB = [&](bf16x8 (&bv)[NH][2], int nsub, int d) {
#pragma unroll
    for (int j = 0; j < NH; ++j)
#pragma unroll
      for (int ks = 0; ks < 2; ++ks) {
        int rb = wc * (16 * WN) + (nsub * NH + j) * 16 + l16;
        bv[j][ks] = *(const bf16x8*)&Bs[d][rb * 64 + (((ks * 4 + quad) ^ (rb & 7)) * 8)];
      }
  };
  auto mm = [&](const bf16x8 (&bv)[NH][2], int mo, int no) {   // one quadrant (T5 wrap)
    __builtin_amdgcn_s_setprio(1);
#pragma unroll
    for (int i = 0; i < 4; ++i)
#pragma unroll
      for (int j = 0; j < NH; ++j)
#pragma unroll
        for (int ks = 0; ks < 2; ++ks)
          acc[mo + i][no + j] =
              __builtin_amdgcn_mfma_f32_16x16x32_bf16(af[i][ks], bv[j][ks], acc[mo + i][no + j], 0, 0, 0);
    __builtin_amdgcn_s_setprio(0);
  };

  const int NT = K / 64;   // 32 (even) for both GEMMs

  // ---- prologue: tiles 0 AND 1 fully staged; wait tile0 (tile1's VMW stay flying)
  stageA(0, 0); stageA(0, 1); stageB(0, 0); stageB(0, 1);
  stageA(1, 0); stageA(1, 1); stageB(1, 0); stageB(1, 1);
  waitvm<VMW>();
  barrier();

#pragma unroll 1
  for (int T = 0; T < NT; T += 2) {
    const bool pf = (T + 2 < NT);   // NT even -> T+2 and T+3 prefetch coincide
    // ================ phases 1-4 : tile T in buf0 ================
    ldA(0, 0); ldB(bv0, 0, 0);           // P1 (no staging)
    barrier(); lgkm0();
    mm(bv0, 0, 0);
    barrier();

    ldB(bv1, 1, 0);                      // P2 (no staging)
    barrier(); lgkm0();
    mm(bv1, 0, NH);
    barrier();

    ldA(1, 0);                           // P3: B(buf0) dead after P2
    if (pf) { stageB(T + 2, 0); stageB(T + 2, 1); }
    barrier(); lgkm0();
    mm(bv1, 4, NH);
    barrier();

    if (pf) {                            // P4: A(buf0) dead after P3
      stageA(T + 2, 0); stageA(T + 2, 1);
      waitvm<VMW>();                     //   tile T+1 landed (issued prev P7/P8)
    } else {
      waitvm<0>();                       //   last iter: drain final tile
    }
    barrier();
    __builtin_amdgcn_sched_barrier(0);
    mm(bv0, 4, 0);
    barrier();

    // ================ phases 5-8 : tile T+1 in buf1 ================
    ldA(0, 1); ldB(bv0, 0, 1);           // P5 (no staging)
    barrier(); lgkm0();
    mm(bv0, 0, 0);
    barrier();

    ldB(bv1, 1, 1);                      // P6 (no staging)
    barrier(); lgkm0();
    mm(bv1, 0, NH);
    barrier();

    ldA(1, 1);                           // P7: B(buf1) dead after P6
    if (pf) { stageB(T + 3, 0); stageB(T + 3, 1); }
    barrier(); lgkm0();
    mm(bv1, 4, NH);
    barrier();

    if (pf) {                            // P8: A(buf1) dead after P7
      stageA(T + 3, 0); stageA(T + 3, 1);
      waitvm<VMW>();                     //   tile T+2 landed (issued P3/P4)
      barrier();
      __builtin_amdgcn_sched_barrier(0);
      mm(bv0, 4, 0);
      barrier();
    } else {
      mm(bv0, 4, 0);                     // last iteration: no more LDS traffic
    }
  }

  // ---- fused RoPE (QKV gemm, Q/K columns only; wave-uniform branch) ----
  if constexpr (ROPE) {
    if (n0 + wc * (16 * WN) < 2560) {
#pragma unroll
      for (int i = 0; i < 8; i++) {
        int t0 = m0 + wr * 128 + i * 16 + quad * 4;
#pragma unroll
        for (int jj = 0; jj < 2; jj++) {
          int d = jj * 16 + l16;            // head-dim 0..31
#pragma unroll
          for (int r = 0; r < 4; r++) {
            float cv = cs[(size_t)(t0 + r) * 32 + d];
            float sv = sn[(size_t)(t0 + r) * 32 + d];
            float x1 = acc[i][jj][r], x2 = acc[i][jj + 2][r];
            acc[i][jj][r] = x1 * cv - x2 * sv;
            acc[i][jj + 2][r] = x2 * cv + x1 * sv;
          }
        }
      }
    }
  }

  // epilogue: C/D layout col=lane&15, row=quad*4+r
#pragma unroll
  for (int i = 0; i < 8; i++) {
    int row = m0 + wr * 128 + i * 16 + quad * 4;
#pragma unroll
    for (int j = 0; j < WN; j++) {
      int col = n0 + wc * (16 * WN) + j * 16 + l16;
#pragma unroll
      for (int r = 0; r < 4; r++) {
        size_t off = (size_t)(row + r) * N + col;
        if constexpr (sizeof(OutT) == 2) C[off] = f2bf(acc[i][j][r]);
        else C[off] = acc[i][j][r];
      }
    }
  }
}

// ---------------- vkt_build: V -> transposed, chunk-swizzled, k-permuted tile images ----
__global__ __launch_bounds__(256) void vkt_build(const u16* __restrict__ qkv,
                                                 u16* __restrict__ vkt) {
  __shared__ u16 Vn[128 * 64];
  const int kt = blockIdx.x, kvh = blockIdx.y, b = blockIdx.z;
  const int tid = threadIdx.x;
  const u16* src = qkv + ((size_t)b * 1024 + kt * 128) * 3072 + 2560 + kvh * 64;
  {
    int tok = tid >> 1, hf = tid & 1;
    const uint4* s4 = (const uint4*)(src + (size_t)tok * 3072 + hf * 32);
    uint4* d4 = (uint4*)&Vn[tok * 64 + hf * 32];
#pragma unroll
    for (int j = 0; j < 4; j++) d4[j] = s4[j];
  }
  __syncthreads();
  u16* img = vkt + ((((size_t)b * 8 + kvh) * 8 + kt) << 13);   // 8192 u16 / image
#pragma unroll
  for (int i = 0; i < 4; i++) {
    int c = tid * 4 + i;                 // chunk index 0..1023
    int dd = c >> 4, chsw = c & 15;
    int ch = chsw ^ (dd & 15);
    u16 tmp[8];
#pragma unroll
    for (int p = 0; p < 8; p++) {
      int col = ch * 8 + p;
      int g = col >> 5, kl = col & 31;
      int kph = ((kl >> 2) & 1) * 16 + ((kl >> 4) & 1) * 8 + ((kl >> 3) & 1) * 4 + (kl & 3);
      tmp[p] = Vn[(g * 32 + kph) * 64 + dd];
    }
    *(uint4*)&img[c * 8] = *(const uint4*)tmp;
  }
}

// ---------------- flash attention v4 ----------------
// Grid (4, 32, 4) = 512 blocks = 2/CU. Two q-tiles per block (qtA=bx, qtB=7-bx):
// 9 tile-steps per block, K/V staged once for both. Transposed-score form,
// max-free exp2 softmax, P kept in registers via the k-permutation baked into
// the VkT images. K and VT double-buffered pure DMA. One barrier/iter.
// LDS: Ks 2x16KB + VT 2x16KB = 64KB -> 2 blocks/CU.
__global__ __launch_bounds__(256, 2) void flash_attn(const u16* __restrict__ qkv,
                                                     const u16* __restrict__ vkt,
                                                     u16* __restrict__ attn) {
  __shared__ u16 Ks[2][128 * 64];
  __shared__ u16 VT[2][64 * 128];

  const int tid = threadIdx.x;
  const int lane = tid & 63, wave = tid >> 6;
  const int quad = lane >> 4, l16 = lane & 15;
  const int qtA = blockIdx.x, qtB = 7 - blockIdx.x;
  const int h = blockIdx.y, b = blockIdx.z, kvh = h >> 2;
  const size_t tokBase = (size_t)b * 1024;
  const int qcol = h * 64, kcol = 2048 + kvh * 64;
  const int srow = tid >> 3, spc = tid & 7, ssc = spc ^ (srow & 7);

  auto stageK = [&](const u16* gbase, u16* L) {   // natural 128x64, swizzled chunks
#pragma unroll
    for (int i = 0; i < 4; i++)
      ld16_lds(gbase + (size_t)(srow + i * 32) * 3072 + ssc * 8, &L[tid * 8 + i * 2048]);
  };
  const u16* vimg = vkt + (((size_t)b * 8 + kvh) << 16);
  auto stageV = [&](int kt, u16* L) {             // pre-swizzled image: linear copy
    const u16* g = vimg + ((size_t)kt << 13);
#pragma unroll
    for (int i = 0; i < 4; i++)
      ld16_lds(g + i * 2048 + tid * 8, &L[tid * 8 + i * 2048]);
  };

  // ---- stage both Q tiles into the K buffers, extract fragments ----
  stageK(qkv + (tokBase + qtA * 128) * 3072 + qcol, Ks[0]);
  stageK(qkv + (tokBase + qtB * 128) * 3072 + qcol, Ks[1]);
  __syncthreads();
  bf16x8 qfA[2][2], qfB[2][2];   // B-frag: n=q=l16, kdim=d contiguous
#pragma unroll
  for (int nq = 0; nq < 2; nq++) {
    int qrow = wave * 32 + nq * 16 + l16;
#pragma unroll
    for (int ks = 0; ks < 2; ks++) {
      int c = (ks * 4 + quad) ^ (qrow & 7);
      qfA[nq][ks] = *(const bf16x8*)&Ks[0][qrow * 64 + c * 8];
      qfB[nq][ks] = *(const bf16x8*)&Ks[1][qrow * 64 + c * 8];
    }
  }
  __syncthreads();   // Q reads done before K DMA overwrites

  float lA[2] = {0.f, 0.f}, lB[2] = {0.f, 0.f};
  f32x4 oA[4][2] = {}, oB[4][2] = {};   // O^T: d=md*16+quad*4+r, q=nq*16+l16

  auto proc = [&](const bf16x8 (&kf)[2][2], const bf16x8 (&va)[4], const bf16x8 (&qf)[2][2],
                  f32x4 (&o)[4][2], float (&lacc)[2], bool msk, int c) {
    f32x4 s[2][2] = {};   // [nq][mkl]: k = (c*2+mkl)*16 + quad*4 + r, q = nq*16+l16
#pragma unroll
    for (int mkl = 0; mkl < 2; mkl++)
#pragma unroll
      for (int ks = 0; ks < 2; ks++) {
        s[0][mkl] = __builtin_amdgcn_mfma_f32_16x16x32_bf16(kf[mkl][ks], qf[0][ks], s[0][mkl], 0, 0, 0);
        s[1][mkl] = __builtin_amdgcn_mfma_f32_16x16x32_bf16(kf[mkl][ks], qf[1][ks], s[1][mkl], 0, 0, 0);
      }
    if (msk) {
#pragma unroll
      for (int nq = 0; nq < 2; nq++) {
        int q = wave * 32 + nq * 16 + l16;
#pragma unroll
        for (int mkl = 0; mkl < 2; mkl++)
#pragma unroll
          for (int r = 0; r < 4; r++)
            if ((c * 2 + mkl) * 16 + quad * 4 + r > q) s[nq][mkl][r] = -3e38f;
      }
    }
    bf16x8 pf[2];
#pragma unroll
    for (int nq = 0; nq < 2; nq++) {
      float a0 = 0.f;
#pragma unroll
      for (int mkl = 0; mkl < 2; mkl++)
#pragma unroll
        for (int r = 0; r < 4; r++) {
          float p = __builtin_amdgcn_exp2f(s[nq][mkl][r]);
          s[nq][mkl][r] = p;
          a0 += p;
        }
      lacc[nq] += a0;
      pf[nq][0] = (__bf16)s[nq][0][0]; pf[nq][1] = (__bf16)s[nq][0][1];
      pf[nq][2] = (__bf16)s[nq][0][2]; pf[nq][3] = (__bf16)s[nq][0][3];
      pf[nq][4] = (__bf16)s[nq][1][0]; pf[nq][5] = (__bf16)s[nq][1][1];
      pf[nq][6] = (__bf16)s[nq][1][2]; pf[nq][7] = (__bf16)s[nq][1][3];
    }
#pragma unroll
    for (int md = 0; md < 4; md++) {
      o[md][0] = __builtin_amdgcn_mfma_f32_16x16x32_bf16(va[md], pf[0], o[md][0], 0, 0, 0);
      o[md][1] = __builtin_amdgcn_mfma_f32_16x16x32_bf16(va[md], pf[1], o[md][1], 0, 0, 0);
    }
  };

  // ---- main loop: double-buffered K + VT DMA, one barrier per iteration ----
  stageK(qkv + tokBase * 3072 + kcol, Ks[0]);
  stageV(0, VT[0]);

  for (int kt = 0; kt <= qtB; kt++) {
    const int cur = kt & 1;
    __syncthreads();   // drains DMA for kt; all waves done with bufs[1-cur]
    if (kt < qtB) {
      stageK(qkv + (tokBase + (kt + 1) * 128) * 3072 + kcol, Ks[1 - cur]);
      stageV(kt + 1, VT[1 - cur]);
    }
    const bool doA = (kt <= qtA), mA = (kt == qtA), mB = (kt == qtB);
    const u16* K = Ks[cur];
    const u16* V = VT[cur];
#pragma unroll
    for (int c = 0; c < 4; c++) {
      bf16x8 kf[2][2];   // A-frag: m=krow=mk*16+l16, kdim=d
#pragma unroll
      for (int mkl = 0; mkl < 2; mkl++) {
        int krow = (c * 2 + mkl) * 16 + l16;
#pragma unroll
        for (int ks = 0; ks < 2; ks++)
          kf[mkl][ks] = *(const bf16x8*)&K[krow * 64 + ((ks * 4 + quad) ^ (krow & 7)) * 8];
      }
      bf16x8 va[4];      // A-frag V^T: m=d=md*16+l16, k-chunk c
#pragma unroll
      for (int md = 0; md < 4; md++) {
        int dd = md * 16 + l16;
        va[md] = *(const bf16x8*)&V[dd * 128 + ((c * 4 + quad) ^ l16) * 8];
      }
      proc(kf, va, qfB, oB, lB, mB, c);
      if (doA) proc(kf, va, qfA, oA, lA, mA, c);
    }
  }

  // ---- epilogue: reduce l across quads (2 shfls), O/l, b64 stores ----
  auto epilogue = [&](const f32x4 (&o)[4][2], const float (&lacc)[2], int qt_tile) {
#pragma unroll
    for (int nq = 0; nq < 2; nq++) {
      float l = lacc[nq];
      l += __shfl_xor(l, 16);
      l += __shfl_xor(l, 32);
      float inv = 1.0f / l;
      int t = qt_tile * 128 + wave * 32 + nq * 16 + l16;
      size_t rowOff = (tokBase + t) * 2048 + qcol;
#pragma unroll
      for (int md = 0; md < 4; md++) {
        bf16x4 w;
        w[0] = (__bf16)(o[md][nq][0] * inv);
        w[1] = (__bf16)(o[md][nq][1] * inv);
        w[2] = (__bf16)(o[md][nq][2] * inv);
        w[3] = (__bf16)(o[md][nq][3] * inv);
        *(bf16x4*)&attn[rowOff + md * 16 + quad * 4] = w;
      }
    }
  };
  epilogue(oB, lB, qtB);
  epilogue(oA, lA, qtA);
}

// ---------------- launch ----------------
extern "C" void kernel_launch(void* const* d_in, const int* in_sizes, int n_in,
                              void* d_out, int out_size, void* d_ws, size_t ws_size,
                              hipStream_t stream) {
  const float* hs = (const float*)d_in[0];
  const float* cs = (const float*)d_in[1];
  const float* sn = (const float*)d_in[2];
  const float* Wq = (const float*)d_in[3];
  const float* Wk = (const float*)d_in[4];
  const float* Wv = (const float*)d_in[5];
  const float* Wo = (const float*)d_in[6];
  float* out = (float*)d_out;

  char* ws = (char*)d_ws;
  u16* hsB   = (u16*)(ws);                  // 4096x2048 bf16 (dead after qkv GEMM)
  u16* vkt   = (u16*)(ws);                  // 4MB VkT images, built after qkv GEMM
  u16* wqkvT = (u16*)(ws + 16777216);       // 3072x2048 bf16 [WqT;WkT;WvT]
  u16* woT   = (u16*)(ws + 29360128);       // 2048x2048 bf16
  u16* qkv   = (u16*)(ws + 37748736);       // 4096x3072 bf16
  u16* attnB = (u16*)(ws + 62914560);       // 4096x2048 bf16

  // attention scale folded into Wq: 1/8 * log2(e)
  const float QSCALE = 0.18033688011112042f;

  convert_f32_bf16<<<8192, 256, 0, stream>>>(hs, hsB, 4096 * 2048 / 4);
  trans_f32_bf16<<<dim3(64, 64), 256, 0, stream>>>(Wq, wqkvT, 2048, 2048, QSCALE);
  trans_f32_bf16<<<dim3(16, 64), 256, 0, stream>>>(Wk, wqkvT + (size_t)2048 * 2048, 2048, 512, 1.0f);
  trans_f32_bf16<<<dim3(16, 64), 256, 0, stream>>>(Wv, wqkvT + (size_t)2560 * 2048, 2048, 512, 1.0f);
  trans_f32_bf16<<<dim3(64, 64), 256, 0, stream>>>(Wo, woT, 2048, 2048, 1.0f);

  // QKV: 256x256 tile, 8-phase deep pipeline, grid 12x16 = 192 blocks (8|192).
  gemm8<u16, true, 256><<<dim3(12, 16), 512, 0, stream>>>(
      hsB, wqkvT, qkv, 4096, 3072, 2048, cs, sn);
  vkt_build<<<dim3(8, 8, 4), 256, 0, stream>>>(qkv, vkt);
  flash_attn<<<dim3(4, 32, 4), 256, 0, stream>>>(qkv, vkt, attnB);
  // Wo: 256x128 tile, 8-phase, grid 16x16 = 256 blocks = 1/CU (8|256).
  gemm8<float, false, 128><<<dim3(16, 16), 512, 0, stream>>>(
      attnB, woT, out, 4096, 2048, 2048, nullptr, nullptr);
}